// Round 7
// baseline (143.702 us; speedup 1.0000x reference)
//
#include <hip/hip_runtime.h>
#include <hip/hip_bf16.h>

#define B 32
#define C 512
#define HW 3136            // 56*56
#define HW4 784            // float4 columns per plane
#define TH 0.01f
#define CPB 16             // channels per block (kernel A)
#define CPW 4              // channels per wave
#define NPG 32             // partial groups = C/CPB

typedef float fx4 __attribute__((ext_vector_type(4)));

// ---------------------------------------------------------------------------
// Kernel A: single-pass partial saliency.
// Block = (b, cg) of 4 waves; each wave owns 4 channels. Per channel:
// lane l holds 12 fx4 (cols l+64j) + 1 tail float (float idx 3072+l) = exactly
// 49 floats -> 3136 = full plane, no masked lanes. Tree-sum + shfl -> alpha,
// FMA same regs into acc. x read from HBM exactly once (NT loads).
// Epilogue: all 4 waves ds_add into component-planar LDS (stride-1 ->
// conflict-free), then 256 threads repack + store partial (cached, B re-reads).
// ---------------------------------------------------------------------------
__global__ __launch_bounds__(256, 4) void partial_kernel(const float* __restrict__ x,
                                                         float* __restrict__ out) {
    const int b  = blockIdx.y;
    const int cg = blockIdx.x;          // 0..NPG-1
    const int t  = threadIdx.x;
    const int l  = t & 63;
    const int w  = t >> 6;

    __shared__ float sal_lds[4 * HW4];  // 12,544 B, component-planar
    for (int i = t; i < 4 * HW4; i += 256) sal_lds[i] = 0.f;
    __syncthreads();

    const float* __restrict__ xf = x + (size_t)b * C * HW;
    const fx4*   __restrict__ xb = (const fx4*)xf;

    fx4 acc[12];
    float acct = 0.f;
    #pragma unroll
    for (int j = 0; j < 12; ++j) acc[j] = (fx4)0.f;

    const int cbase = cg * CPB + w * CPW;
    for (int i = 0; i < CPW; ++i) {
        const int c = cbase + i;
        const fx4* __restrict__ p = xb + (size_t)c * HW4;
        fx4 v[12];
        #pragma unroll
        for (int j = 0; j < 12; ++j) v[j] = __builtin_nontemporal_load(p + l + 64 * j);
        const float vt = __builtin_nontemporal_load(xf + (size_t)c * HW + 3072 + l);

        // tree-sum of this lane's 49 floats
        float ps[12];
        #pragma unroll
        for (int j = 0; j < 12; ++j) ps[j] = (v[j].x + v[j].y) + (v[j].z + v[j].w);
        const float q0 = (ps[0] + ps[1]) + (ps[2] + ps[3]);
        const float q1 = (ps[4] + ps[5]) + (ps[6] + ps[7]);
        const float q2 = (ps[8] + ps[9]) + (ps[10] + ps[11]);
        float s = (q0 + q1) + (q2 + vt);
        #pragma unroll
        for (int off = 1; off < 64; off <<= 1) s += __shfl_xor(s, off);
        const float a = s * (1.0f / (float)HW);   // alpha[b,c]

        #pragma unroll
        for (int j = 0; j < 12; ++j) acc[j] += v[j] * a;
        acct += vt * a;
    }

    // scatter-add into planar LDS: addr = comp*784 + col, consecutive lanes
    // hit consecutive dwords -> conflict-free ds_add_f32.
    #pragma unroll
    for (int j = 0; j < 12; ++j) {
        const int col = l + 64 * j;
        atomicAdd(&sal_lds[0 * HW4 + col], acc[j].x);
        atomicAdd(&sal_lds[1 * HW4 + col], acc[j].y);
        atomicAdd(&sal_lds[2 * HW4 + col], acc[j].z);
        atomicAdd(&sal_lds[3 * HW4 + col], acc[j].w);
    }
    atomicAdd(&sal_lds[(l & 3) * HW4 + 768 + (l >> 2)], acct);
    __syncthreads();

    // cooperative repack + cached store (partials are re-read by kernel B)
    fx4* __restrict__ dst = (fx4*)(out + (size_t)b * C * HW) + (size_t)cg * HW4;
    for (int col = t; col < HW4; col += 256) {
        fx4 r;
        r.x = sal_lds[0 * HW4 + col];
        r.y = sal_lds[1 * HW4 + col];
        r.z = sal_lds[2 * HW4 + col];
        r.w = sal_lds[3 * HW4 + col];
        dst[col] = r;
    }
}

// ---------------------------------------------------------------------------
// Kernel B: sum 32 partials -> sal, then expansion (R5-verbatim, best known).
// Block = (b, tile of 16 fx4 cols). Partials live in d_out planes co=0..31,
// read before this block overwrites them (read->sync->write within block).
// ---------------------------------------------------------------------------
__global__ __launch_bounds__(256) void out_kernel(const float* __restrict__ w,
                                                  const float* __restrict__ scale_p,
                                                  const float* __restrict__ wf_p,
                                                  float* __restrict__ out) {
    const int b    = blockIdx.y;
    const int tile = blockIdx.x;               // 0..48
    const int t    = threadIdx.x;
    const int hw4  = t & 15;
    const int pg2  = t >> 4;                   // 0..15 -> partials 2*pg2, 2*pg2+1
    const int lane = t & 63;
    const int wid  = t >> 6;

    const fx4* __restrict__ P =
        (const fx4*)(out + (size_t)b * C * HW) + tile * 16 + hw4;
    fx4 s = P[(size_t)(2 * pg2) * HW4] + P[(size_t)(2 * pg2 + 1) * HW4];

    // reduce the 4 pg2-groups in this wave (lane deltas 16, 32)
    s.x += __shfl_xor(s.x, 16); s.y += __shfl_xor(s.y, 16);
    s.z += __shfl_xor(s.z, 16); s.w += __shfl_xor(s.w, 16);
    s.x += __shfl_xor(s.x, 32); s.y += __shfl_xor(s.y, 32);
    s.z += __shfl_xor(s.z, 32); s.w += __shfl_xor(s.w, 32);

    __shared__ fx4 red[4][16];
    if (lane < 16) red[wid][lane] = s;
    __syncthreads();

    __shared__ fx4 sal_sm[16];
    if (t < 16) {
        sal_sm[t] = ((red[0][t] + red[1][t]) + (red[2][t] + red[3][t])) *
                    (1.0f / (float)C);
    }
    __syncthreads();

    const float scale = scale_p[0];
    const float wf    = wf_p[0];
    const float out_zero = 1.0f - 0.5f * wf;   // fm == 0 path
    const fx4 s4 = sal_sm[hw4];

    fx4* __restrict__ ob = (fx4*)(out + (size_t)b * C * HW) + tile * 16 + hw4;
    const int c0 = pg2 * 32;                   // each group covers its 32 co's

    #pragma unroll 4
    for (int k = 0; k < 32; ++k) {
        const int co = c0 + k;
        const float wc = w[co];
        fx4 r;
        float fm;
        fm = s4.x * wc;
        r.x = (fm > TH) ? 1.0f - wf / (1.0f + __expf(-scale * fm)) : out_zero;
        fm = s4.y * wc;
        r.y = (fm > TH) ? 1.0f - wf / (1.0f + __expf(-scale * fm)) : out_zero;
        fm = s4.z * wc;
        r.z = (fm > TH) ? 1.0f - wf / (1.0f + __expf(-scale * fm)) : out_zero;
        fm = s4.w * wc;
        r.w = (fm > TH) ? 1.0f - wf / (1.0f + __expf(-scale * fm)) : out_zero;
        __builtin_nontemporal_store(r, ob + (size_t)co * HW4);
    }
}

extern "C" void kernel_launch(void* const* d_in, const int* in_sizes, int n_in,
                              void* d_out, int out_size, void* d_ws, size_t ws_size,
                              hipStream_t stream) {
    const float* x      = (const float*)d_in[0];
    const float* conv_w = (const float*)d_in[1];   // 512 floats
    const float* scale  = (const float*)d_in[2];
    const float* wf     = (const float*)d_in[3];
    float* out = (float*)d_out;

    dim3 gridA(NPG, B);                            // 32 x 32 = 1024 blocks
    partial_kernel<<<gridA, 256, 0, stream>>>(x, out);

    dim3 gridB(HW4 / 16, B);                       // 49 x 32 = 1568 blocks
    out_kernel<<<gridB, 256, 0, stream>>>(conv_w, scale, wf, out);
}